// Round 2
// 611.407 us; speedup vs baseline: 6.4132x; 6.4132x over previous
//
#include <hip/hip_runtime.h>

// LiftSplatShoot voxel pooling, B=1, N=6, D=41, H=64, W=176, C=32, grid 200x200x1.
// nprime = 2,770,944 points. rank = ix*200 + iy (nx2=1, B=1).
// out[c*40000 + ix*200 + iy] = sum over points in voxel (ix,iy) of x[p][c].
//
// R6: old one-atomic-per-channel scatter = 88.7M contended f32 atomics;
// rocprof: WRITE_SIZE=2.2GB (~24B RMW traffic per atomic), VALUBusy 0.1%,
// HBM 8.6% -> atomic-transaction-count bound. New scheme: per-voxel linked
// lists, ONE atomicExch per kept point (~2.08M, 43x fewer atomics), then a
// zero-atomic gather: one wave per voxel, 2 chains x 32 channels, register
// accumulation, coalesced 128B x-row reads.
// R7 hardening (container died with no diagnostics): chain walk is bounded
// (<= nprime links) and every chased index is range-checked, so a poisoned
// next[]/head2[] can stall nothing and read nothing wild.

#define NVOX 40000
#define NCH  32

__device__ __forceinline__ void atomic_add_agent(float* p, float v) {
    __hip_atomic_fetch_add(p, v, __ATOMIC_RELAXED, __HIP_MEMORY_SCOPE_AGENT);
}

__device__ __forceinline__ int voxel_of(const float* __restrict__ geom, int p) {
    // Exact reference arithmetic: t = (g - (bx - dx/2)) / dx, trunc toward zero.
    float gx = geom[3 * (size_t)p + 0];
    float gy = geom[3 * (size_t)p + 1];
    float gz = geom[3 * (size_t)p + 2];
    float tx = (gx + 50.0f) / 0.5f;   // lo_x = -50 exact; /0.5 exact
    float ty = (gy + 50.0f) / 0.5f;
    float tz = (gz + 10.0f) / 20.0f;  // correctly-rounded IEEE f32 division
    int ix = (int)tx;  // trunc toward zero == astype(int32); (-1,0) -> 0 kept
    int iy = (int)ty;
    int iz = (int)tz;
    if (!((ix >= 0) && (ix < 200) && (iy >= 0) && (iy < 200) && (iz == 0)))
        return -1;
    return ix * 200 + iy;
}

// ---------------- fast path: linked-list build + per-voxel gather ----------

// head2: [2][NVOX] chain heads (two chains per voxel, split by point parity,
// halves the serial chase depth in the gather). next: [nprime].
__global__ void __launch_bounds__(256)
lss_build(const float* __restrict__ geom, int* __restrict__ head2,
          int* __restrict__ next, int nprime) {
    int p = blockIdx.x * blockDim.x + threadIdx.x;
    if (p >= nprime) return;
    int v = voxel_of(geom, p);
    if (v < 0) return;
    int slot = (p & 1) * NVOX + v;
    int old = __hip_atomic_exchange(&head2[slot], p,
                                    __ATOMIC_RELAXED, __HIP_MEMORY_SCOPE_AGENT);
    next[p] = old;   // consumed only by the next kernel launch -> no race
}

// One wave per voxel. lane = half*32 + c: half-wave walks one chain, lane's
// channel accumulates in a register. Chains avg ~26 deep; next[] (11MB) is
// L2/L3 resident; x row loads are contiguous 128B per point.
__global__ void __launch_bounds__(256)
lss_gather(const float* __restrict__ x, const int* __restrict__ head2,
           const int* __restrict__ next, float* __restrict__ out, int nprime) {
    int wv = blockIdx.x * (blockDim.x >> 6) + (threadIdx.x >> 6);  // voxel
    if (wv >= NVOX) return;
    int lane = threadIdx.x & 63;
    int half = lane >> 5;   // which chain
    int c    = lane & 31;   // channel

    float acc = 0.0f;
    int p = head2[half * NVOX + wv];
    int left = nprime;                   // hard bound: chains are acyclic by
    while (p >= 0 && p < nprime && left-- > 0) {  // construction; this is hang
        acc += x[(size_t)p * NCH + c];            // insurance only.
        p = next[p];        // 32 lanes load same addr -> one line, broadcast
    }
    acc += __shfl_xor(acc, 32);          // combine the two chains
    if (lane < 32)
        out[(size_t)c * NVOX + wv] = acc;  // (C, 200, 200) layout, all written
}

// ---------------- fallback path (proven R5 kernel) -------------------------

__global__ void __launch_bounds__(256)
lss_scatter(const float* __restrict__ geom,
            const float* __restrict__ x,
            float* __restrict__ acc, int nprime, int c0, int cg) {
    int p = blockIdx.x * blockDim.x + threadIdx.x;
    if (p >= nprime) return;
    int v = voxel_of(geom, p);
    if (v < 0) return;

    float* dst = acc + (size_t)v * cg;
    const float* row = x + (size_t)p * NCH + c0;

    int k4 = cg >> 2;                       // cg is a power of 2
    const float4* rv = (const float4*)row;  // 16B-aligned (c0 multiple of cg >= 4)
    for (int k = 0; k < k4; ++k) {
        float4 vv = rv[k];
        atomic_add_agent(dst + 4 * k + 0, vv.x);
        atomic_add_agent(dst + 4 * k + 1, vv.y);
        atomic_add_agent(dst + 4 * k + 2, vv.z);
        atomic_add_agent(dst + 4 * k + 3, vv.w);
    }
    for (int k = k4 << 2; k < cg; ++k)      // cg in {1,2} fallback
        atomic_add_agent(dst + k, row[k]);
}

__global__ void __launch_bounds__(256)
lss_finalize(const float* __restrict__ acc, float* __restrict__ out,
             int c0, int cg) {
    int t = blockIdx.x * blockDim.x + threadIdx.x;
    if (t >= NVOX * cg) return;
    int cl = t / NVOX;      // local channel within group
    int s  = t - cl * NVOX; // voxel = ix*200+iy
    out[(size_t)(c0 + cl) * NVOX + s] = acc[(size_t)s * cg + cl];
}

// ---------------------------------------------------------------------------

extern "C" void kernel_launch(void* const* d_in, const int* in_sizes, int n_in,
                              void* d_out, int out_size, void* d_ws, size_t ws_size,
                              hipStream_t stream) {
    const float* geom = (const float*)d_in[0];
    const float* x    = (const float*)d_in[1];
    int gsz = in_sizes[0], xsz = in_sizes[1];
    if (gsz > xsz) {  // defensive: geom (nprime*3) is the smaller input
        const float* tmp = geom; geom = x; x = tmp;
        int t2 = gsz; gsz = xsz; xsz = t2;
    }
    float* out = (float*)d_out;
    int nprime = xsz / NCH;  // 2,770,944
    int threads = 256;

    size_t need = (size_t)(2 * NVOX + nprime) * sizeof(int);  // ~11.4 MB
    if (ws_size >= need) {
        int* head2 = (int*)d_ws;
        int* next  = head2 + 2 * NVOX;
        // all-ones bytes == -1 sentinel heads
        hipMemsetAsync(head2, 0xFF, (size_t)2 * NVOX * sizeof(int), stream);
        int blocks_build = (nprime + threads - 1) / threads;
        lss_build<<<blocks_build, threads, 0, stream>>>(geom, head2, next, nprime);
        int blocks_gather = (NVOX + (threads / 64) - 1) / (threads / 64);  // 10001
        lss_gather<<<blocks_gather, threads, 0, stream>>>(x, head2, next, out, nprime);
        return;
    }

    // fallback: channel-grouped atomic scatter (R5)
    float* acc = (float*)d_ws;
    int cg = NCH;
    while (cg > 1 && (size_t)NVOX * cg * sizeof(float) > ws_size) cg >>= 1;
    int blocks_scatter = (nprime + threads - 1) / threads;
    for (int c0 = 0; c0 < NCH; c0 += cg) {
        hipMemsetAsync(acc, 0, (size_t)NVOX * cg * sizeof(float), stream);
        lss_scatter<<<blocks_scatter, threads, 0, stream>>>(geom, x, acc, nprime, c0, cg);
        int total = NVOX * cg;
        lss_finalize<<<(total + threads - 1) / threads, threads, 0, stream>>>(acc, out, c0, cg);
    }
}